// Round 2
// baseline (1383.051 us; speedup 1.0000x reference)
//
#include <hip/hip_runtime.h>
#include <hip/hip_cooperative_groups.h>
#include <math.h>

namespace cg = cooperative_groups;

#define NN 100000
#define DD 128
#define CC 16
#define SS 16
#define EE 3200000
#define KK 64
#define NIT 4
#define CNT_STRIDE 32   // pad class counters 128B apart
#define NB 32           // stage-A slices per class
#define SLMAX 4096      // max stage-A slice (pow2 >= ceil(NN/NB)=3125)
#define MM (NB * KK)    // stage-B merge size = 2048
#define EB ((EE + 255) / 256)
#define GRID 512        // cooperative grid: 2 blocks/CU guaranteed resident
#define INF_STAMP 0x7fffffff

typedef unsigned long long ull;

// order-preserving double -> uint64 bijection (and exact inverse)
__device__ inline ull ordkey(double d) {
    long long b = __double_as_longlong(d);
    return (b < 0) ? ~(ull)b : ((ull)b | 0x8000000000000000ULL);
}
__device__ inline double keyord(ull u) {
    long long b = (u & 0x8000000000000000ULL)
                    ? (long long)(u & 0x7FFFFFFFFFFFFFFFULL)
                    : (long long)~u;
    return __longlong_as_double(b);
}
// total order: "a earlier than b" == key desc, node asc (== lax.top_k order)
__device__ inline bool gt(ull ka, int na, ull kb, int nb) {
    return (ka > kb) || (ka == kb && na < nb);
}

// in-wave bitonic sort of 64 (key,node) pairs, descending by gt. zero barriers.
__device__ inline void wsort64(ull& k, int& n, int lane) {
    for (int k2 = 2; k2 <= 64; k2 <<= 1) {
        for (int j = k2 >> 1; j; j >>= 1) {
            ull ok = __shfl_xor(k, j, 64);
            int on = __shfl_xor(n, j, 64);
            bool isLow = (lane & j) == 0;
            bool d = (k2 == 64) || ((lane & k2) == 0);
            bool wantMax = (d == isLow);
            if (wantMax == gt(ok, on, k, n)) { k = ok; n = on; }
        }
    }
}
// in-wave bitonic merge (input bitonic), descending by gt
__device__ inline void wmerge64(ull& k, int& n, int lane) {
    for (int j = 32; j; j >>= 1) {
        ull ok = __shfl_xor(k, j, 64);
        int on = __shfl_xor(n, j, 64);
        bool wantMax = (lane & j) == 0;
        if (wantMax == gt(ok, on, k, n)) { k = ok; n = on; }
    }
}

// -------------------- fused cooperative kernel: LDS union --------------------

union alignas(16) SMem {
    struct {                       // memory-step phase (37.4 KB)
        float  inp[KK][DD + 1];
        int    rowS[KK];
        double q[DD];
        double lg[KK];
        double sr[KK];
        double pre[DD];
        double red[DD];
    } ms;
    struct {                       // candidate phase (41.2 KB)
        int    pair[256 * 16];
        short  prank[256 * 16];
        double hxnL[CC * 129];
        int    lcnt[CC];
        int    base[CC];
        int    npair;
    } cd;
    struct {                       // top-k / merge phases (48 KB)
        ull ks[SLMAX];
        int ns[SLMAX];
    } tp;
};

__global__ __launch_bounds__(256, 2)
void k_fused(const float* __restrict__ es, const int* __restrict__ edge,
             const int* __restrict__ seeds, const float* __restrict__ Wm,
             float* __restrict__ out,
             int* __restrict__ known, unsigned* __restrict__ cate,
             unsigned* __restrict__ nbr,
             double* __restrict__ hx, double* __restrict__ hxn,
             int* __restrict__ last, int* __restrict__ cnt,
             ull* __restrict__ tkey, int* __restrict__ tnode,
             int* __restrict__ cidx, ull* __restrict__ ckey, int cap) {
    cg::grid_group grid = cg::this_grid();
    __shared__ SMem sm;
    int tid = threadIdx.x, bid = blockIdx.x;
    int wave = tid >> 6, lane = tid & 63;

    // ---- phase 0: state reset (norms are fused into scoring; no es pass) ----
    for (int n = bid * 256 + tid; n < NN; n += GRID * 256) {
        known[n] = INF_STAMP;
        cate[n] = 0;
        nbr[n] = 0;
    }
    grid.sync();
    if (bid == 0 && tid < CC * SS) {
        int n = seeds[tid];
        known[n] = 0;                       // stamp: known since iteration 0
        atomicOr(&cate[n], 1u << (tid / SS));
    }
    grid.sync();

    for (int t = 0; t < NIT; ++t) {
        // ================= phase M (blocks 0..15) + E (rest) =================
        if (bid < CC) {
            int c = bid;
            if (tid == 0) cnt[c * CNT_STRIDE] = 0;   // fused counter reset
            int k = (t == 0) ? SS : KK;
            if (tid < KK) {
                sm.ms.lg[tid] = -1.0e308;
                if (tid < k)
                    sm.ms.rowS[tid] = (t == 0) ? seeds[c * SS + tid] : last[c * KK + tid];
            }
            __syncthreads();
            for (int i = tid; i < k * DD; i += 256)
                sm.ms.inp[i >> 7][i & 127] = es[(long)sm.ms.rowS[i >> 7] * DD + (i & 127)];
            __syncthreads();
            if (tid < DD) {
                if (t == 0) {
                    double s = 0;
                    for (int j = 0; j < k; ++j) s += (double)sm.ms.inp[j][tid];
                    sm.ms.q[tid] = s / (double)k;
                } else {
                    sm.ms.q[tid] = hx[c * DD + tid];
                }
            }
            __syncthreads();
            if (tid < k) {
                double s = 0;
                for (int i = 0; i < DD; ++i) s += (double)sm.ms.inp[tid][i] * sm.ms.q[i];
                sm.ms.lg[tid] = s / sqrt((double)DD);
            }
            __syncthreads();
            if (tid < KK) sm.ms.sr[tid] = sm.ms.lg[tid];
            __syncthreads();
            for (int st = 32; st > 0; st >>= 1) {
                if (tid < st) sm.ms.sr[tid] = fmax(sm.ms.sr[tid], sm.ms.sr[tid + st]);
                __syncthreads();
            }
            double mx = sm.ms.sr[0];
            __syncthreads();
            if (tid < KK) {
                double e = (tid < k) ? exp(sm.ms.lg[tid] - mx) : 0.0;
                sm.ms.lg[tid] = e; sm.ms.sr[tid] = e;
            }
            __syncthreads();
            for (int st = 32; st > 0; st >>= 1) {
                if (tid < st) sm.ms.sr[tid] += sm.ms.sr[tid + st];
                __syncthreads();
            }
            double smv = sm.ms.sr[0];
            __syncthreads();
            if (tid < KK) sm.ms.lg[tid] /= smv;
            __syncthreads();
            if (tid < DD) {
                double ctx = 0;
                for (int j = 0; j < k; ++j) ctx += sm.ms.lg[j] * (double)sm.ms.inp[j][tid];
                sm.ms.pre[tid] = (t == 0) ? ctx : (ctx + sm.ms.q[tid]);
            }
            __syncthreads();
            double h = 0;
            if (tid < DD) {
                for (int i = 0; i < DD; ++i) h += sm.ms.pre[i] * (double)Wm[i * DD + tid];
                h = tanh(h);
                sm.ms.red[tid] = h * h;
            }
            __syncthreads();
            for (int st = 64; st > 0; st >>= 1) {
                if (tid < st) sm.ms.red[tid] += sm.ms.red[tid + st];
                __syncthreads();
            }
            if (tid < DD) {
                double inv = 1.0 / (sqrt(sm.ms.red[0]) + 1e-8);
                hx[c * DD + tid] = h;
                hxn[c * DD + tid] = h * inv;
                out[2 * NIT * CC * KK + t * CC * DD + c * DD + tid] = (float)h;  // hxes
            }
        } else {
            // ---- edge scan: nbr[dst] |= cate[src] ----
            for (long e = (long)(bid - CC) * 256 + tid; e < EE;
                 e += (long)(GRID - CC) * 256) {
                int s = edge[e];
                unsigned m = cate[s];
                if (m) atomicOr(&nbr[edge[EE + e]], m);
            }
        }
        grid.sync();

        // ================= phase C: candidate scoring (norm fused) ============
        if (bid * 256 < NN) {
            for (int i = tid; i < CC * DD; i += 256)
                sm.cd.hxnL[(i >> 7) * 129 + (i & 127)] = hxn[i];
            if (tid < CC) sm.cd.lcnt[tid] = 0;
            if (tid == 0) sm.cd.npair = 0;
            __syncthreads();

            int n = bid * 256 + tid;
            unsigned m = 0;
            if (n < NN && known[n] > t) m = nbr[n];   // stamp > t <=> unknown at iter t
            while (m) {
                int c = __ffs(m) - 1;
                m &= m - 1;
                int r = atomicAdd(&sm.cd.lcnt[c], 1);
                int p = atomicAdd(&sm.cd.npair, 1);
                sm.cd.pair[p] = (n << 4) | c;
                sm.cd.prank[p] = (short)r;
            }
            __syncthreads();

            if (tid < CC && sm.cd.lcnt[tid] > 0)
                sm.cd.base[tid] = atomicAdd(&cnt[tid * CNT_STRIDE], sm.cd.lcnt[tid]);
            __syncthreads();

            int np = sm.cd.npair;
            for (int t2 = tid; t2 < np; t2 += 256) {
                int pk = sm.cd.pair[t2];
                int nn = pk >> 4, c = pk & 15;
                const float4* row = (const float4*)(es + (long)nn * DD);
                const double* h = &sm.cd.hxnL[c * 129];
                double s = 0, p2 = 0;
                #pragma unroll
                for (int i = 0; i < 32; ++i) {
                    float4 v = row[i];
                    double vx = v.x, vy = v.y, vz = v.z, vw = v.w;
                    s  += vx * h[4 * i + 0] + vy * h[4 * i + 1]
                        + vz * h[4 * i + 2] + vw * h[4 * i + 3];
                    p2 += vx * vx + vy * vy + vz * vz + vw * vw;
                }
                int pos = sm.cd.base[c] + (int)sm.cd.prank[t2];
                if (pos < cap) {
                    cidx[(long)c * cap + pos] = nn;
                    ckey[(long)c * cap + pos] = ordkey(s / (sqrt(p2) + 1e-8));
                }
            }
        }
        grid.sync();

        // ================= phase T: per-slice exact top-64 ====================
        {
            int c = bid / NB, b = bid % NB;
            int count = min(cnt[c * CNT_STRIDE], cap);
            int per = (count + NB - 1) / NB;
            int start = b * per;
            int mcnt = min(per, count - start);
            int sl = 64;
            while (sl < per) sl <<= 1;
            int nruns = sl >> 6;
            for (int r = wave; r < nruns; r += 4) {
                int i = (r << 6) + lane;
                ull k; int n2;
                if (i < mcnt) { k = ckey[(long)c * cap + start + i];
                                n2 = cidx[(long)c * cap + start + i]; }
                else          { k = 0ULL; n2 = 0x7FFFFFFF; }
                wsort64(k, n2, lane);
                sm.tp.ks[i] = k; sm.tp.ns[i] = n2;
            }
            __syncthreads();
            for (int step = 1; step < nruns; step <<= 1) {
                int npair2 = nruns / (2 * step);
                for (int pr = wave; pr < npair2; pr += 4) {
                    int ra = pr * 2 * step, rb = ra + step;
                    ull ka = sm.tp.ks[(ra << 6) + lane];      int na = sm.tp.ns[(ra << 6) + lane];
                    ull kb = sm.tp.ks[(rb << 6) + 63 - lane]; int nb2 = sm.tp.ns[(rb << 6) + 63 - lane];
                    if (gt(kb, nb2, ka, na)) { ka = kb; na = nb2; }
                    wmerge64(ka, na, lane);
                    sm.tp.ks[(ra << 6) + lane] = ka; sm.tp.ns[(ra << 6) + lane] = na;
                }
                __syncthreads();
            }
            if (tid < KK) {
                tkey[(long)c * MM + b * KK + tid] = sm.tp.ks[tid];
                tnode[(long)c * MM + b * KK + tid] = sm.tp.ns[tid];
            }
        }
        grid.sync();

        // ================= phase U: merge 32 runs -> top-64, apply updates ====
        if (bid < CC) {
            int c = bid;
            for (int i = tid; i < MM; i += 256) {
                sm.tp.ks[i] = tkey[(long)c * MM + i];
                sm.tp.ns[i] = tnode[(long)c * MM + i];
            }
            __syncthreads();
            for (int step = 1; step < NB; step <<= 1) {
                int npair2 = NB / (2 * step);
                for (int pr = wave; pr < npair2; pr += 4) {
                    int ra = pr * 2 * step, rb = ra + step;
                    ull ka = sm.tp.ks[(ra << 6) + lane];      int na = sm.tp.ns[(ra << 6) + lane];
                    ull kb = sm.tp.ks[(rb << 6) + 63 - lane]; int nb2 = sm.tp.ns[(rb << 6) + 63 - lane];
                    if (gt(kb, nb2, ka, na)) { ka = kb; na = nb2; }
                    wmerge64(ka, na, lane);
                    sm.tp.ks[(ra << 6) + lane] = ka; sm.tp.ns[(ra << 6) + lane] = na;
                }
                __syncthreads();
            }
            int count = min(cnt[c * CNT_STRIDE], cap);
            int nsel = min(count, KK);
            if (tid < KK && tid < nsel) {
                int n = sm.tp.ns[tid];
                out[t * CC * KK + c * KK + tid] = (float)keyord(sm.tp.ks[tid]);   // outs
                out[NIT * CC * KK + t * CC * KK + c * KK + tid] = (float)n;       // exps
                last[c * KK + tid] = n;
                known[n] = t + 1;               // stamp: invisible to this iteration's tests
                atomicOr(&cate[n], 1u << c);
            }
            // fill path (fewer valid than K): lowest-index invalid nodes, prob=-1e9.
            if (tid == 0 && nsel < KK) {
                int r = nsel;
                for (int n = 0; n < NN && r < KK; ++n) {
                    bool valid = ((nbr[n] >> c) & 1u) && (known[n] > t);
                    if (!valid) {
                        out[t * CC * KK + c * KK + r] = -1e9f;
                        out[NIT * CC * KK + t * CC * KK + c * KK + r] = (float)n;
                        last[c * KK + r] = n;
                        known[n] = t + 1;
                        atomicOr(&cate[n], 1u << c);
                        ++r;
                    }
                }
            }
        }
        grid.sync();
    }
}

// ==================== fallback path: verified 18-launch pipeline ====================

__global__ __launch_bounds__(256)
void k_init(const float* __restrict__ es, double* __restrict__ inv_norm,
            int* __restrict__ known, unsigned* __restrict__ cate,
            unsigned* __restrict__ nbr) {
    int wave = threadIdx.x >> 6, lane = threadIdx.x & 63;
    int n = blockIdx.x * 4 + wave;
    if (n >= NN) return;
    float a = es[(long)n * DD + lane];
    float b = es[(long)n * DD + 64 + lane];
    double p = (double)a * (double)a + (double)b * (double)b;
    for (int o = 32; o > 0; o >>= 1) p += __shfl_xor(p, o, 64);
    if (lane == 0) {
        inv_norm[n] = 1.0 / (sqrt(p) + 1e-8);
        known[n] = INF_STAMP;
        cate[n] = 0;
        nbr[n] = 0;
    }
}

__global__ void k_seed(const int* __restrict__ seeds, int* __restrict__ known,
                       unsigned* __restrict__ cate) {
    int i = threadIdx.x;
    if (i < CC * SS) {
        int n = seeds[i];
        known[n] = 0;
        atomicOr(&cate[n], 1u << (i / SS));
    }
}

__global__ __launch_bounds__(256)
void k_memedge(const float* __restrict__ es, const float* __restrict__ Wm,
               const int* __restrict__ seeds, const int* __restrict__ last,
               double* __restrict__ hx, double* __restrict__ hxn,
               float* __restrict__ out, int* __restrict__ cnt,
               const int* __restrict__ edge, const unsigned* __restrict__ cate,
               unsigned* __restrict__ nbr, int t) {
    __shared__ float  inp[KK][DD + 1];
    __shared__ int    rowS[KK];
    __shared__ double q[DD];
    __shared__ double lg[KK];
    __shared__ double sr[KK];
    __shared__ double pre[DD];
    __shared__ double red[DD];
    int tid = threadIdx.x;

    if (blockIdx.x >= CC) {
        long e = (long)(blockIdx.x - CC) * 256 + tid;
        if (e < EE) {
            int s = edge[e];
            unsigned m = cate[s];
            if (m) {
                int d = edge[EE + e];
                atomicOr(&nbr[d], m);
            }
        }
        return;
    }

    int c = blockIdx.x;
    if (tid == 0) cnt[c * CNT_STRIDE] = 0;
    int k = (t == 0) ? SS : KK;
    if (tid < KK) {
        lg[tid] = -1.0e308;
        if (tid < k) rowS[tid] = (t == 0) ? seeds[c * SS + tid] : last[c * KK + tid];
    }
    __syncthreads();
    for (int i = tid; i < k * DD; i += 256)
        inp[i >> 7][i & 127] = es[(long)rowS[i >> 7] * DD + (i & 127)];
    __syncthreads();
    if (tid < DD) {
        if (t == 0) {
            double s = 0;
            for (int j = 0; j < k; ++j) s += (double)inp[j][tid];
            q[tid] = s / (double)k;
        } else {
            q[tid] = hx[c * DD + tid];
        }
    }
    __syncthreads();
    if (tid < k) {
        double s = 0;
        for (int i = 0; i < DD; ++i) s += (double)inp[tid][i] * q[i];
        lg[tid] = s / sqrt((double)DD);
    }
    __syncthreads();
    if (tid < KK) sr[tid] = lg[tid];
    __syncthreads();
    for (int st = 32; st > 0; st >>= 1) {
        if (tid < st) sr[tid] = fmax(sr[tid], sr[tid + st]);
        __syncthreads();
    }
    double mx = sr[0];
    __syncthreads();
    if (tid < KK) {
        double e = (tid < k) ? exp(lg[tid] - mx) : 0.0;
        lg[tid] = e; sr[tid] = e;
    }
    __syncthreads();
    for (int st = 32; st > 0; st >>= 1) {
        if (tid < st) sr[tid] += sr[tid + st];
        __syncthreads();
    }
    double sm = sr[0];
    __syncthreads();
    if (tid < KK) lg[tid] /= sm;
    __syncthreads();
    if (tid < DD) {
        double ctx = 0;
        for (int j = 0; j < k; ++j) ctx += lg[j] * (double)inp[j][tid];
        pre[tid] = (t == 0) ? ctx : (ctx + q[tid]);
    }
    __syncthreads();
    double h = 0;
    if (tid < DD) {
        for (int i = 0; i < DD; ++i) h += pre[i] * (double)Wm[i * DD + tid];
        h = tanh(h);
        red[tid] = h * h;
    }
    __syncthreads();
    for (int st = 64; st > 0; st >>= 1) {
        if (tid < st) red[tid] += red[tid + st];
        __syncthreads();
    }
    if (tid < DD) {
        double inv = 1.0 / (sqrt(red[0]) + 1e-8);
        hx[c * DD + tid] = h;
        hxn[c * DD + tid] = h * inv;
        out[2 * NIT * CC * KK + t * CC * DD + c * DD + tid] = (float)h;
    }
}

__global__ __launch_bounds__(256)
void k_cand(const float* __restrict__ es, const double* __restrict__ inv_norm,
            const int* __restrict__ known, const unsigned* __restrict__ nbr,
            const double* __restrict__ hxn,
            int* __restrict__ cnt, int* __restrict__ cidx,
            ull* __restrict__ ckey, int cap, int t) {
    __shared__ int    pair[256 * 16];
    __shared__ short  prank[256 * 16];
    __shared__ double hxnL[CC * 129];
    __shared__ int    lcnt[CC];
    __shared__ int    base[CC];
    __shared__ int    npair;
    int tid = threadIdx.x;

    for (int i = tid; i < CC * DD; i += 256)
        hxnL[(i >> 7) * 129 + (i & 127)] = hxn[i];
    if (tid < CC) lcnt[tid] = 0;
    if (tid == 0) npair = 0;
    __syncthreads();

    int n = blockIdx.x * 256 + tid;
    unsigned m = 0;
    if (n < NN && known[n] > t) m = nbr[n];
    while (m) {
        int c = __ffs(m) - 1;
        m &= m - 1;
        int r = atomicAdd(&lcnt[c], 1);
        int p = atomicAdd(&npair, 1);
        pair[p] = (n << 4) | c;
        prank[p] = (short)r;
    }
    __syncthreads();

    if (tid < CC && lcnt[tid] > 0)
        base[tid] = atomicAdd(&cnt[tid * CNT_STRIDE], lcnt[tid]);
    __syncthreads();

    int np = npair;
    for (int t2 = tid; t2 < np; t2 += 256) {
        int pk = pair[t2];
        int nn = pk >> 4, c = pk & 15;
        const float4* row = (const float4*)(es + (long)nn * DD);
        const double* h = &hxnL[c * 129];
        double s = 0;
        #pragma unroll
        for (int i = 0; i < 32; ++i) {
            float4 v = row[i];
            s += (double)v.x * h[4 * i + 0] + (double)v.y * h[4 * i + 1]
               + (double)v.z * h[4 * i + 2] + (double)v.w * h[4 * i + 3];
        }
        int pos = base[c] + (int)prank[t2];
        if (pos < cap) {
            cidx[(long)c * cap + pos] = nn;
            ckey[(long)c * cap + pos] = ordkey(s * inv_norm[nn]);
        }
    }
}

__global__ __launch_bounds__(256)
void k_top(const int* __restrict__ cnt, const int* __restrict__ cidx,
           const ull* __restrict__ ckey, int cap,
           ull* __restrict__ tkey, int* __restrict__ tnode) {
    __shared__ ull ks[SLMAX];
    __shared__ int ns[SLMAX];
    int c = blockIdx.x / NB, b = blockIdx.x % NB;
    int tid = threadIdx.x, wave = tid >> 6, lane = tid & 63;
    int count = min(cnt[c * CNT_STRIDE], cap);
    int per = (count + NB - 1) / NB;
    int start = b * per;
    int m = min(per, count - start);
    int sl = 64;
    while (sl < per) sl <<= 1;
    int nruns = sl >> 6;
    for (int r = wave; r < nruns; r += 4) {
        int i = (r << 6) + lane;
        ull k; int n;
        if (i < m) { k = ckey[(long)c * cap + start + i]; n = cidx[(long)c * cap + start + i]; }
        else       { k = 0ULL; n = 0x7FFFFFFF; }
        wsort64(k, n, lane);
        ks[i] = k; ns[i] = n;
    }
    __syncthreads();
    for (int step = 1; step < nruns; step <<= 1) {
        int npair2 = nruns / (2 * step);
        for (int pr = wave; pr < npair2; pr += 4) {
            int ra = pr * 2 * step, rb = ra + step;
            ull ka = ks[(ra << 6) + lane];       int na = ns[(ra << 6) + lane];
            ull kb = ks[(rb << 6) + 63 - lane];  int nb2 = ns[(rb << 6) + 63 - lane];
            if (gt(kb, nb2, ka, na)) { ka = kb; na = nb2; }
            wmerge64(ka, na, lane);
            ks[(ra << 6) + lane] = ka; ns[(ra << 6) + lane] = na;
        }
        __syncthreads();
    }
    if (tid < KK) {
        tkey[(long)c * MM + b * KK + tid] = ks[tid];
        tnode[(long)c * MM + b * KK + tid] = ns[tid];
    }
}

__global__ __launch_bounds__(256)
void k_mergeupd(const int* __restrict__ cnt,
                const ull* __restrict__ tkey, const int* __restrict__ tnode,
                int* __restrict__ known, const unsigned* __restrict__ nbr,
                unsigned* __restrict__ cate, int* __restrict__ last,
                float* __restrict__ out, int cap, int t) {
    __shared__ ull ks[MM];
    __shared__ int ns[MM];
    int c = blockIdx.x, tid = threadIdx.x, wave = tid >> 6, lane = tid & 63;
    for (int i = tid; i < MM; i += 256) {
        ks[i] = tkey[(long)c * MM + i];
        ns[i] = tnode[(long)c * MM + i];
    }
    __syncthreads();
    for (int step = 1; step < NB; step <<= 1) {
        int npair2 = NB / (2 * step);
        for (int pr = wave; pr < npair2; pr += 4) {
            int ra = pr * 2 * step, rb = ra + step;
            ull ka = ks[(ra << 6) + lane];       int na = ns[(ra << 6) + lane];
            ull kb = ks[(rb << 6) + 63 - lane];  int nb2 = ns[(rb << 6) + 63 - lane];
            if (gt(kb, nb2, ka, na)) { ka = kb; na = nb2; }
            wmerge64(ka, na, lane);
            ks[(ra << 6) + lane] = ka; ns[(ra << 6) + lane] = na;
        }
        __syncthreads();
    }
    int count = min(cnt[c * CNT_STRIDE], cap);
    int nsel = min(count, KK);
    if (tid < KK && tid < nsel) {
        int n = ns[tid];
        out[t * CC * KK + c * KK + tid] = (float)keyord(ks[tid]);
        out[NIT * CC * KK + t * CC * KK + c * KK + tid] = (float)n;
        last[c * KK + tid] = n;
        known[n] = t + 1;
        atomicOr(&cate[n], 1u << c);
    }
    if (tid == 0 && nsel < KK) {
        int r = nsel;
        for (int n = 0; n < NN && r < KK; ++n) {
            bool valid = ((nbr[n] >> c) & 1u) && (known[n] > t);
            if (!valid) {
                out[t * CC * KK + c * KK + r] = -1e9f;
                out[NIT * CC * KK + t * CC * KK + c * KK + r] = (float)n;
                last[c * KK + r] = n;
                known[n] = t + 1;
                atomicOr(&cate[n], 1u << c);
                ++r;
            }
        }
    }
}

// -------------------- host launcher --------------------

extern "C" void kernel_launch(void* const* d_in, const int* in_sizes, int n_in,
                              void* d_out, int out_size, void* d_ws, size_t ws_size,
                              hipStream_t stream) {
    const float* es    = (const float*)d_in[0];
    const int*   edge  = (const int*)d_in[1];
    const int*   seeds = (const int*)d_in[2];
    const float* W     = (const float*)d_in[3];
    float* out = (float*)d_out;

    char* p = (char*)d_ws;
    auto alloc = [&](size_t bytes) -> char* {
        char* r = p;
        p += (bytes + 255) & ~(size_t)255;
        return r;
    };
    double*   inv_norm = (double*)alloc((size_t)NN * 8);
    int*      known    = (int*)alloc((size_t)NN * 4);
    unsigned* cate     = (unsigned*)alloc((size_t)NN * 4);
    unsigned* nbr      = (unsigned*)alloc((size_t)NN * 4);
    double*   hx       = (double*)alloc(CC * DD * 8);
    double*   hxn      = (double*)alloc(CC * DD * 8);
    int*      last     = (int*)alloc(CC * KK * 4);
    int*      cnt      = (int*)alloc(CC * CNT_STRIDE * 4);
    ull*      tkey     = (ull*)alloc((size_t)CC * MM * 8);
    int*      tnode    = (int*)alloc((size_t)CC * MM * 4);
    size_t used = (size_t)(p - (char*)d_ws);
    size_t rem = (ws_size > used + 8192) ? (ws_size - used - 8192) : 0;
    long capl = (long)(rem / (CC * 12));
    if (capl > NN) capl = NN;
    if (capl < 1) capl = 1;
    int cap = (int)capl;
    int*    cidx = (int*)alloc((size_t)CC * cap * 4);
    ull*    ckey = (ull*)alloc((size_t)CC * cap * 8);

    void* args[] = {
        (void*)&es, (void*)&edge, (void*)&seeds, (void*)&W, (void*)&out,
        (void*)&known, (void*)&cate, (void*)&nbr, (void*)&hx, (void*)&hxn,
        (void*)&last, (void*)&cnt, (void*)&tkey, (void*)&tnode,
        (void*)&cidx, (void*)&ckey, (void*)&cap
    };
    hipError_t err = hipLaunchCooperativeKernel((void*)k_fused, dim3(GRID),
                                                dim3(256), args, 0, stream);
    if (err == hipSuccess) return;

    // fallback: verified multi-launch pipeline
    k_init<<<(NN + 3) / 4, 256, 0, stream>>>(es, inv_norm, known, cate, nbr);
    k_seed<<<1, 256, 0, stream>>>(seeds, known, cate);
    for (int t = 0; t < NIT; ++t) {
        k_memedge<<<CC + EB, 256, 0, stream>>>(es, W, seeds, last, hx, hxn, out,
                                               cnt, edge, cate, nbr, t);
        k_cand<<<(NN + 255) / 256, 256, 0, stream>>>(es, inv_norm, known, nbr, hxn,
                                                     cnt, cidx, ckey, cap, t);
        k_top<<<CC * NB, 256, 0, stream>>>(cnt, cidx, ckey, cap, tkey, tnode);
        k_mergeupd<<<CC, 256, 0, stream>>>(cnt, tkey, tnode, known, nbr,
                                           cate, last, out, cap, t);
    }
}

// Round 3
// 375.603 us; speedup vs baseline: 3.6822x; 3.6822x over previous
//
#include <hip/hip_runtime.h>
#include <math.h>

#define NN 100000
#define DD 128
#define CC 16
#define SS 16
#define EE 3200000
#define KK 64
#define NIT 4
#define CNT_STRIDE 32   // pad class counters 128B apart
#define EBLK 2048       // grid-stride blocks for edge scan
#define INF_STAMP 0x7fffffff

typedef unsigned long long ull;

// order-preserving double -> uint64 bijection (and exact inverse)
__device__ inline ull ordkey(double d) {
    long long b = __double_as_longlong(d);
    return (b < 0) ? ~(ull)b : ((ull)b | 0x8000000000000000ULL);
}
__device__ inline double keyord(ull u) {
    long long b = (u & 0x8000000000000000ULL)
                    ? (long long)(u & 0x7FFFFFFFFFFFFFFFULL)
                    : (long long)~u;
    return __longlong_as_double(b);
}
// total order: "a earlier than b" == key desc, node asc (== lax.top_k order)
__device__ inline bool gt(ull ka, int na, ull kb, int nb) {
    return (ka > kb) || (ka == kb && na < nb);
}

// in-wave bitonic sort of 64 (key,node) pairs, descending by gt. zero barriers.
__device__ inline void wsort64(ull& k, int& n, int lane) {
    for (int k2 = 2; k2 <= 64; k2 <<= 1) {
        for (int j = k2 >> 1; j; j >>= 1) {
            ull ok = __shfl_xor(k, j, 64);
            int on = __shfl_xor(n, j, 64);
            bool isLow = (lane & j) == 0;
            bool d = (k2 == 64) || ((lane & k2) == 0);
            bool wantMax = (d == isLow);
            if (wantMax == gt(ok, on, k, n)) { k = ok; n = on; }
        }
    }
}
// in-wave bitonic merge (input bitonic), descending by gt
__device__ inline void wmerge64(ull& k, int& n, int lane) {
    for (int j = 32; j; j >>= 1) {
        ull ok = __shfl_xor(k, j, 64);
        int on = __shfl_xor(n, j, 64);
        bool wantMax = (lane & j) == 0;
        if (wantMax == gt(ok, on, k, n)) { k = ok; n = on; }
    }
}

// ---------- init: state reset + seed marking fused (no es pass; norms live in k_cand) ----------

__global__ __launch_bounds__(256)
void k_init(const int* __restrict__ seeds, int* __restrict__ known,
            unsigned* __restrict__ cate, unsigned* __restrict__ nbr) {
    __shared__ int sd[CC * SS];
    int tid = threadIdx.x;
    if (tid < CC * SS) sd[tid] = seeds[tid];
    __syncthreads();
    int wave = tid >> 6, lane = tid & 63;
    int n = blockIdx.x * 4 + wave;
    if (n >= NN) return;
    // does this node appear in the seed list? (4 entries per lane covers all 256)
    unsigned m = 0;
    #pragma unroll
    for (int e = lane; e < CC * SS; e += 64)
        if (sd[e] == n) m |= 1u << (e / SS);
    for (int o = 32; o > 0; o >>= 1) m |= __shfl_xor(m, o, 64);
    if (lane == 0) {
        known[n] = m ? 0 : INF_STAMP;   // seeds known since iteration 0
        cate[n] = m;
        nbr[n] = 0;
    }
}

// ------------- fused: memory step (blocks 0..15) + edge pass (rest, grid-stride) -------------
// independent within an iteration: mem reads es/seeds/last/hx, edge reads cate -> nbr

__global__ __launch_bounds__(256)
void k_memedge(const float* __restrict__ es, const float* __restrict__ Wm,
               const int* __restrict__ seeds, const int* __restrict__ last,
               double* __restrict__ hx, double* __restrict__ hxn,
               float* __restrict__ out, int* __restrict__ cnt,
               const int* __restrict__ edge, const unsigned* __restrict__ cate,
               unsigned* __restrict__ nbr, int t) {
    __shared__ float  inp[KK][DD + 1];   // pad: conflict-free column reads
    __shared__ int    rowS[KK];
    __shared__ double q[DD];
    __shared__ double lg[KK];
    __shared__ double sr[KK];
    __shared__ double pre[DD];
    __shared__ double red[DD];
    int tid = threadIdx.x;

    if (blockIdx.x >= CC) {
        // ---- edge branch: nbr[dst] |= cate[src] ----
        for (long e = (long)(blockIdx.x - CC) * 256 + tid; e < EE;
             e += (long)EBLK * 256) {
            int s = edge[e];
            unsigned m = cate[s];
            if (m) atomicOr(&nbr[edge[EE + e]], m);
        }
        return;
    }

    // ---- memory-step branch (block-uniform; barriers legal) ----
    int c = blockIdx.x;
    if (tid == 0) cnt[c * CNT_STRIDE] = 0;     // fused counter reset
    int k = (t == 0) ? SS : KK;
    if (tid < KK) {
        lg[tid] = -1.0e308;
        if (tid < k) rowS[tid] = (t == 0) ? seeds[c * SS + tid] : last[c * KK + tid];
    }
    __syncthreads();
    for (int i = tid; i < k * DD; i += 256)
        inp[i >> 7][i & 127] = es[(long)rowS[i >> 7] * DD + (i & 127)];
    __syncthreads();
    if (tid < DD) {
        if (t == 0) {
            double s = 0;
            for (int j = 0; j < k; ++j) s += (double)inp[j][tid];
            q[tid] = s / (double)k;
        } else {
            q[tid] = hx[c * DD + tid];
        }
    }
    __syncthreads();
    if (tid < k) {
        double s = 0;
        for (int i = 0; i < DD; ++i) s += (double)inp[tid][i] * q[i];
        lg[tid] = s / sqrt((double)DD);
    }
    __syncthreads();
    if (tid < KK) sr[tid] = lg[tid];
    __syncthreads();
    for (int st = 32; st > 0; st >>= 1) {
        if (tid < st) sr[tid] = fmax(sr[tid], sr[tid + st]);
        __syncthreads();
    }
    double mx = sr[0];
    __syncthreads();
    if (tid < KK) {
        double e = (tid < k) ? exp(lg[tid] - mx) : 0.0;
        lg[tid] = e; sr[tid] = e;
    }
    __syncthreads();
    for (int st = 32; st > 0; st >>= 1) {
        if (tid < st) sr[tid] += sr[tid + st];
        __syncthreads();
    }
    double sm = sr[0];
    __syncthreads();
    if (tid < KK) lg[tid] /= sm;
    __syncthreads();
    if (tid < DD) {
        double ctx = 0;
        for (int j = 0; j < k; ++j) ctx += lg[j] * (double)inp[j][tid];
        pre[tid] = (t == 0) ? ctx : (ctx + q[tid]);
    }
    __syncthreads();
    double h = 0;
    if (tid < DD) {
        for (int i = 0; i < DD; ++i) h += pre[i] * (double)Wm[i * DD + tid];
        h = tanh(h);
        red[tid] = h * h;
    }
    __syncthreads();
    for (int st = 64; st > 0; st >>= 1) {
        if (tid < st) red[tid] += red[tid + st];
        __syncthreads();
    }
    if (tid < DD) {
        double inv = 1.0 / (sqrt(red[0]) + 1e-8);
        hx[c * DD + tid] = h;
        hxn[c * DD + tid] = h * inv;
        out[2 * NIT * CC * KK + t * CC * DD + c * DD + tid] = (float)h;  // hxes
    }
}

// ---------- candidate scoring: block-aggregated, thread-per-pair, norm fused ----------

__global__ __launch_bounds__(256)
void k_cand(const float* __restrict__ es,
            const int* __restrict__ known, const unsigned* __restrict__ nbr,
            const double* __restrict__ hxn,
            int* __restrict__ cnt, int* __restrict__ cidx,
            ull* __restrict__ ckey, int cap, int t) {
    __shared__ int    pair[256 * 16];
    __shared__ short  prank[256 * 16];
    __shared__ double hxnL[CC * 129];
    __shared__ int    lcnt[CC];
    __shared__ int    base[CC];
    __shared__ int    npair;
    int tid = threadIdx.x;

    for (int i = tid; i < CC * DD; i += 256)
        hxnL[(i >> 7) * 129 + (i & 127)] = hxn[i];
    if (tid < CC) lcnt[tid] = 0;
    if (tid == 0) npair = 0;
    __syncthreads();

    int n = blockIdx.x * 256 + tid;
    unsigned m = 0;
    if (n < NN && known[n] > t) m = nbr[n];   // stamp > t  <=>  unknown at iter t
    while (m) {
        int c = __ffs(m) - 1;
        m &= m - 1;
        int r = atomicAdd(&lcnt[c], 1);
        int p = atomicAdd(&npair, 1);
        pair[p] = (n << 4) | c;
        prank[p] = (short)r;
    }
    __syncthreads();

    if (tid < CC && lcnt[tid] > 0)
        base[tid] = atomicAdd(&cnt[tid * CNT_STRIDE], lcnt[tid]);
    __syncthreads();

    int np = npair;
    for (int t2 = tid; t2 < np; t2 += 256) {
        int pk = pair[t2];
        int nn = pk >> 4, c = pk & 15;
        const float4* row = (const float4*)(es + (long)nn * DD);
        const double* h = &hxnL[c * 129];
        double s = 0, p2 = 0;
        #pragma unroll
        for (int i = 0; i < 32; ++i) {
            float4 v = row[i];
            double vx = v.x, vy = v.y, vz = v.z, vw = v.w;
            s  += vx * h[4 * i + 0] + vy * h[4 * i + 1]
                + vz * h[4 * i + 2] + vw * h[4 * i + 3];
            p2 += vx * vx + vy * vy + vz * vz + vw * vw;
        }
        int pos = base[c] + (int)prank[t2];
        if (pos < cap) {
            cidx[(long)c * cap + pos] = nn;
            ckey[(long)c * cap + pos] = ordkey(s / (sqrt(p2) + 1e-8));
        }
    }
}

// ---------- single-stage top-64 + updates: per-wave streaming, cross-wave merge ----------
// replaces k_top (512 blocks) + k_mergeupd (16 blocks): one 16-block kernel.

__global__ __launch_bounds__(256)
void k_topupd(const int* __restrict__ cnt, const int* __restrict__ cidx,
              const ull* __restrict__ ckey,
              int* __restrict__ known, const unsigned* __restrict__ nbr,
              unsigned* __restrict__ cate, int* __restrict__ last,
              float* __restrict__ out, int cap, int t) {
    __shared__ ull ksh[4 * KK];
    __shared__ int nsh[4 * KK];
    int c = blockIdx.x, tid = threadIdx.x, wave = tid >> 6, lane = tid & 63;
    int count = min(cnt[c * CNT_STRIDE], cap);

    // per-wave streaming exact top-64 (register-resident running list, desc)
    ull rk = 0ULL; int rn = 0x7FFFFFFF;
    int nch = (count + 63) >> 6;
    for (int ch = wave; ch < nch; ch += 4) {
        int i = (ch << 6) + lane;
        ull k; int n;
        if (i < count) { k = ckey[(long)c * cap + i]; n = cidx[(long)c * cap + i]; }
        else           { k = 0ULL; n = 0x7FFFFFFF; }
        wsort64(k, n, lane);                          // chunk sorted desc
        ull ok = __shfl(k, 63 - lane, 64);            // reversed chunk
        int on = __shfl(n, 63 - lane, 64);
        if (gt(ok, on, rk, rn)) { rk = ok; rn = on; } // bitonic split -> winners
        wmerge64(rk, rn, lane);                       // running top-64 restored
    }
    ksh[(wave << 6) + lane] = rk;
    nsh[(wave << 6) + lane] = rn;
    __syncthreads();

    // merge 4 wave-lists (2-step tree, same verified pattern)
    for (int step = 1; step < 4; step <<= 1) {
        int npair2 = 4 / (2 * step);
        if (wave < npair2) {
            int ra = wave * 2 * step, rb = ra + step;
            ull ka = ksh[(ra << 6) + lane];       int na = nsh[(ra << 6) + lane];
            ull kb = ksh[(rb << 6) + 63 - lane];  int nb2 = nsh[(rb << 6) + 63 - lane];
            if (gt(kb, nb2, ka, na)) { ka = kb; na = nb2; }
            wmerge64(ka, na, lane);
            ksh[(ra << 6) + lane] = ka; nsh[(ra << 6) + lane] = na;
        }
        __syncthreads();
    }

    int nsel = min(count, KK);
    if (tid < KK && tid < nsel) {
        int n = nsh[tid];
        out[t * CC * KK + c * KK + tid] = (float)keyord(ksh[tid]);     // outs
        out[NIT * CC * KK + t * CC * KK + c * KK + tid] = (float)n;    // exps
        last[c * KK + tid] = n;
        known[n] = t + 1;               // stamp: invisible to this iteration's tests
        atomicOr(&cate[n], 1u << c);
    }
    // fill path (fewer valid than K): lowest-index invalid nodes, prob=-1e9.
    // stamp test (known[n] <= t) sees only pre-iteration state -> race-free vs
    // concurrent t+1 stamps from other classes (matches reference semantics).
    if (tid == 0 && nsel < KK) {
        int r = nsel;
        for (int n = 0; n < NN && r < KK; ++n) {
            bool valid = ((nbr[n] >> c) & 1u) && (known[n] > t);
            if (!valid) {
                out[t * CC * KK + c * KK + r] = -1e9f;
                out[NIT * CC * KK + t * CC * KK + c * KK + r] = (float)n;
                last[c * KK + r] = n;
                known[n] = t + 1;
                atomicOr(&cate[n], 1u << c);
                ++r;
            }
        }
    }
}

// -------------------- host launcher: 13 launches total --------------------

extern "C" void kernel_launch(void* const* d_in, const int* in_sizes, int n_in,
                              void* d_out, int out_size, void* d_ws, size_t ws_size,
                              hipStream_t stream) {
    const float* es    = (const float*)d_in[0];
    const int*   edge  = (const int*)d_in[1];
    const int*   seeds = (const int*)d_in[2];
    const float* W     = (const float*)d_in[3];
    float* out = (float*)d_out;

    char* p = (char*)d_ws;
    auto alloc = [&](size_t bytes) -> char* {
        char* r = p;
        p += (bytes + 255) & ~(size_t)255;
        return r;
    };
    int*      known    = (int*)alloc((size_t)NN * 4);
    unsigned* cate     = (unsigned*)alloc((size_t)NN * 4);
    unsigned* nbr      = (unsigned*)alloc((size_t)NN * 4);
    double*   hx       = (double*)alloc(CC * DD * 8);
    double*   hxn      = (double*)alloc(CC * DD * 8);
    int*      last     = (int*)alloc(CC * KK * 4);
    int*      cnt      = (int*)alloc(CC * CNT_STRIDE * 4);
    size_t used = (size_t)(p - (char*)d_ws);
    size_t rem = (ws_size > used + 8192) ? (ws_size - used - 8192) : 0;
    long capl = (long)(rem / (CC * 12));
    if (capl > NN) capl = NN;
    if (capl < 1) capl = 1;
    int cap = (int)capl;
    int*    cidx = (int*)alloc((size_t)CC * cap * 4);
    ull*    ckey = (ull*)alloc((size_t)CC * cap * 8);

    k_init<<<(NN + 3) / 4, 256, 0, stream>>>(seeds, known, cate, nbr);

    for (int t = 0; t < NIT; ++t) {
        k_memedge<<<CC + EBLK, 256, 0, stream>>>(es, W, seeds, last, hx, hxn, out,
                                                 cnt, edge, cate, nbr, t);
        k_cand<<<(NN + 255) / 256, 256, 0, stream>>>(es, known, nbr, hxn,
                                                     cnt, cidx, ckey, cap, t);
        k_topupd<<<CC, 256, 0, stream>>>(cnt, cidx, ckey, known, nbr,
                                         cate, last, out, cap, t);
    }
}

// Round 4
// 303.889 us; speedup vs baseline: 4.5512x; 1.2360x over previous
//
#include <hip/hip_runtime.h>
#include <math.h>

#define NN 100000
#define DD 128
#define CC 16
#define SS 16
#define EE 3200000
#define KK 64
#define NIT 4
#define CNT_STRIDE 32   // pad class counters 128B apart
#define NB 32           // stage-A slices per class
#define SLMAX 4096      // max stage-A slice (pow2 >= ceil(NN/NB)=3125)
#define MM (NB * KK)    // stage-B merge size = 2048
#define EBLK 2048       // grid-stride blocks for edge scan
#define INF_STAMP 0x7fffffff

typedef unsigned long long ull;

// order-preserving double -> uint64 bijection (and exact inverse)
__device__ inline ull ordkey(double d) {
    long long b = __double_as_longlong(d);
    return (b < 0) ? ~(ull)b : ((ull)b | 0x8000000000000000ULL);
}
__device__ inline double keyord(ull u) {
    long long b = (u & 0x8000000000000000ULL)
                    ? (long long)(u & 0x7FFFFFFFFFFFFFFFULL)
                    : (long long)~u;
    return __longlong_as_double(b);
}
// total order: "a earlier than b" == key desc, node asc (== lax.top_k order)
__device__ inline bool gt(ull ka, int na, ull kb, int nb) {
    return (ka > kb) || (ka == kb && na < nb);
}

// in-wave bitonic sort of 64 (key,node) pairs, descending by gt. zero barriers.
__device__ inline void wsort64(ull& k, int& n, int lane) {
    for (int k2 = 2; k2 <= 64; k2 <<= 1) {
        for (int j = k2 >> 1; j; j >>= 1) {
            ull ok = __shfl_xor(k, j, 64);
            int on = __shfl_xor(n, j, 64);
            bool isLow = (lane & j) == 0;
            bool d = (k2 == 64) || ((lane & k2) == 0);
            bool wantMax = (d == isLow);
            if (wantMax == gt(ok, on, k, n)) { k = ok; n = on; }
        }
    }
}
// in-wave bitonic merge (input bitonic), descending by gt
__device__ inline void wmerge64(ull& k, int& n, int lane) {
    for (int j = 32; j; j >>= 1) {
        ull ok = __shfl_xor(k, j, 64);
        int on = __shfl_xor(n, j, 64);
        bool wantMax = (lane & j) == 0;
        if (wantMax == gt(ok, on, k, n)) { k = ok; n = on; }
    }
}

// ---------- init: state reset + seed marking fused (no es pass; norms live in k_cand) ----------

__global__ __launch_bounds__(256)
void k_init(const int* __restrict__ seeds, int* __restrict__ known,
            unsigned* __restrict__ cate, unsigned* __restrict__ nbr) {
    __shared__ int sd[CC * SS];
    int tid = threadIdx.x;
    if (tid < CC * SS) sd[tid] = seeds[tid];
    __syncthreads();
    int wave = tid >> 6, lane = tid & 63;
    int n = blockIdx.x * 4 + wave;
    if (n >= NN) return;
    // does this node appear in the seed list? (4 entries per lane covers all 256)
    unsigned m = 0;
    #pragma unroll
    for (int e = lane; e < CC * SS; e += 64)
        if (sd[e] == n) m |= 1u << (e / SS);
    for (int o = 32; o > 0; o >>= 1) m |= __shfl_xor(m, o, 64);
    if (lane == 0) {
        known[n] = m ? 0 : INF_STAMP;   // seeds known since iteration 0
        cate[n] = m;
        nbr[n] = 0;
    }
}

// ------------- fused: memory step (blocks 0..15) + edge pass (rest, grid-stride) -------------
// independent within an iteration: mem reads es/seeds/last/hx, edge reads cate -> nbr

__global__ __launch_bounds__(256)
void k_memedge(const float* __restrict__ es, const float* __restrict__ Wm,
               const int* __restrict__ seeds, const int* __restrict__ last,
               double* __restrict__ hx, double* __restrict__ hxn,
               float* __restrict__ out, int* __restrict__ cnt,
               const int* __restrict__ edge, const unsigned* __restrict__ cate,
               unsigned* __restrict__ nbr, int t) {
    __shared__ float  inp[KK][DD + 1];   // pad: conflict-free column reads
    __shared__ int    rowS[KK];
    __shared__ double q[DD];
    __shared__ double lg[KK];
    __shared__ double sr[KK];
    __shared__ double pre[DD];
    __shared__ double red[DD];
    int tid = threadIdx.x;

    if (blockIdx.x >= CC) {
        // ---- edge branch: nbr[dst] |= cate[src] ----
        for (long e = (long)(blockIdx.x - CC) * 256 + tid; e < EE;
             e += (long)EBLK * 256) {
            int s = edge[e];
            unsigned m = cate[s];
            if (m) atomicOr(&nbr[edge[EE + e]], m);
        }
        return;
    }

    // ---- memory-step branch (block-uniform; barriers legal) ----
    int c = blockIdx.x;
    if (tid == 0) cnt[c * CNT_STRIDE] = 0;     // fused counter reset
    int k = (t == 0) ? SS : KK;
    if (tid < KK) {
        lg[tid] = -1.0e308;
        if (tid < k) rowS[tid] = (t == 0) ? seeds[c * SS + tid] : last[c * KK + tid];
    }
    __syncthreads();
    for (int i = tid; i < k * DD; i += 256)
        inp[i >> 7][i & 127] = es[(long)rowS[i >> 7] * DD + (i & 127)];
    __syncthreads();
    if (tid < DD) {
        if (t == 0) {
            double s = 0;
            for (int j = 0; j < k; ++j) s += (double)inp[j][tid];
            q[tid] = s / (double)k;
        } else {
            q[tid] = hx[c * DD + tid];
        }
    }
    __syncthreads();
    if (tid < k) {
        double s = 0;
        for (int i = 0; i < DD; ++i) s += (double)inp[tid][i] * q[i];
        lg[tid] = s / sqrt((double)DD);
    }
    __syncthreads();
    if (tid < KK) sr[tid] = lg[tid];
    __syncthreads();
    for (int st = 32; st > 0; st >>= 1) {
        if (tid < st) sr[tid] = fmax(sr[tid], sr[tid + st]);
        __syncthreads();
    }
    double mx = sr[0];
    __syncthreads();
    if (tid < KK) {
        double e = (tid < k) ? exp(lg[tid] - mx) : 0.0;
        lg[tid] = e; sr[tid] = e;
    }
    __syncthreads();
    for (int st = 32; st > 0; st >>= 1) {
        if (tid < st) sr[tid] += sr[tid + st];
        __syncthreads();
    }
    double sm = sr[0];
    __syncthreads();
    if (tid < KK) lg[tid] /= sm;
    __syncthreads();
    if (tid < DD) {
        double ctx = 0;
        for (int j = 0; j < k; ++j) ctx += lg[j] * (double)inp[j][tid];
        pre[tid] = (t == 0) ? ctx : (ctx + q[tid]);
    }
    __syncthreads();
    double h = 0;
    if (tid < DD) {
        for (int i = 0; i < DD; ++i) h += pre[i] * (double)Wm[i * DD + tid];
        h = tanh(h);
        red[tid] = h * h;
    }
    __syncthreads();
    for (int st = 64; st > 0; st >>= 1) {
        if (tid < st) red[tid] += red[tid + st];
        __syncthreads();
    }
    if (tid < DD) {
        double inv = 1.0 / (sqrt(red[0]) + 1e-8);
        hx[c * DD + tid] = h;
        hxn[c * DD + tid] = h * inv;
        out[2 * NIT * CC * KK + t * CC * DD + c * DD + tid] = (float)h;  // hxes
    }
}

// ---------- candidate scoring: block-aggregated, thread-per-pair, norm fused ----------

__global__ __launch_bounds__(256)
void k_cand(const float* __restrict__ es,
            const int* __restrict__ known, const unsigned* __restrict__ nbr,
            const double* __restrict__ hxn,
            int* __restrict__ cnt, int* __restrict__ cidx,
            ull* __restrict__ ckey, int cap, int t) {
    __shared__ int    pair[256 * 16];
    __shared__ short  prank[256 * 16];
    __shared__ double hxnL[CC * 129];
    __shared__ int    lcnt[CC];
    __shared__ int    base[CC];
    __shared__ int    npair;
    int tid = threadIdx.x;

    for (int i = tid; i < CC * DD; i += 256)
        hxnL[(i >> 7) * 129 + (i & 127)] = hxn[i];
    if (tid < CC) lcnt[tid] = 0;
    if (tid == 0) npair = 0;
    __syncthreads();

    int n = blockIdx.x * 256 + tid;
    unsigned m = 0;
    if (n < NN && known[n] > t) m = nbr[n];   // stamp > t  <=>  unknown at iter t
    while (m) {
        int c = __ffs(m) - 1;
        m &= m - 1;
        int r = atomicAdd(&lcnt[c], 1);
        int p = atomicAdd(&npair, 1);
        pair[p] = (n << 4) | c;
        prank[p] = (short)r;
    }
    __syncthreads();

    if (tid < CC && lcnt[tid] > 0)
        base[tid] = atomicAdd(&cnt[tid * CNT_STRIDE], lcnt[tid]);
    __syncthreads();

    int np = npair;
    for (int t2 = tid; t2 < np; t2 += 256) {
        int pk = pair[t2];
        int nn = pk >> 4, c = pk & 15;
        const float4* row = (const float4*)(es + (long)nn * DD);
        const double* h = &hxnL[c * 129];
        double s = 0, p2 = 0;
        #pragma unroll
        for (int i = 0; i < 32; ++i) {
            float4 v = row[i];
            double vx = v.x, vy = v.y, vz = v.z, vw = v.w;
            s  += vx * h[4 * i + 0] + vy * h[4 * i + 1]
                + vz * h[4 * i + 2] + vw * h[4 * i + 3];
            p2 += vx * vx + vy * vy + vz * vz + vw * vw;
        }
        int pos = base[c] + (int)prank[t2];
        if (pos < cap) {
            cidx[(long)c * cap + pos] = nn;
            ckey[(long)c * cap + pos] = ordkey(s / (sqrt(p2) + 1e-8));
        }
    }
}

// ---------- stage A: per-slice exact top-64 (in-wave sorts + in-wave merge tree) ----------

__global__ __launch_bounds__(256)
void k_top(const int* __restrict__ cnt, const int* __restrict__ cidx,
           const ull* __restrict__ ckey, int cap,
           ull* __restrict__ tkey, int* __restrict__ tnode) {
    __shared__ ull ks[SLMAX];
    __shared__ int ns[SLMAX];
    int c = blockIdx.x / NB, b = blockIdx.x % NB;
    int tid = threadIdx.x, wave = tid >> 6, lane = tid & 63;
    int count = min(cnt[c * CNT_STRIDE], cap);
    int per = (count + NB - 1) / NB;
    int start = b * per;
    int m = min(per, count - start);
    int sl = 64;
    while (sl < per) sl <<= 1;
    int nruns = sl >> 6;
    // sort each 64-run inside one wave (registers, no barriers)
    for (int r = wave; r < nruns; r += 4) {
        int i = (r << 6) + lane;
        ull k; int n;
        if (i < m) { k = ckey[(long)c * cap + start + i]; n = cidx[(long)c * cap + start + i]; }
        else       { k = 0ULL; n = 0x7FFFFFFF; }
        wsort64(k, n, lane);
        ks[i] = k; ns[i] = n;
    }
    __syncthreads();
    // merge tree: each pair handled by one wave; winner written over run A
    for (int step = 1; step < nruns; step <<= 1) {
        int npair2 = nruns / (2 * step);
        for (int pr = wave; pr < npair2; pr += 4) {
            int ra = pr * 2 * step, rb = ra + step;
            ull ka = ks[(ra << 6) + lane];       int na = ns[(ra << 6) + lane];
            ull kb = ks[(rb << 6) + 63 - lane];  int nb2 = ns[(rb << 6) + 63 - lane];
            if (gt(kb, nb2, ka, na)) { ka = kb; na = nb2; }   // bitonic split -> winners
            wmerge64(ka, na, lane);
            ks[(ra << 6) + lane] = ka; ns[(ra << 6) + lane] = na;
        }
        __syncthreads();
    }
    if (tid < KK) {
        tkey[(long)c * MM + b * KK + tid] = ks[tid];
        tnode[(long)c * MM + b * KK + tid] = ns[tid];
    }
}

// ---------- stage B: merge 32 sorted runs -> top-64, apply updates + outputs (fused) ----------

__global__ __launch_bounds__(256)
void k_mergeupd(const int* __restrict__ cnt,
                const ull* __restrict__ tkey, const int* __restrict__ tnode,
                int* __restrict__ known, const unsigned* __restrict__ nbr,
                unsigned* __restrict__ cate, int* __restrict__ last,
                float* __restrict__ out, int cap, int t) {
    __shared__ ull ks[MM];
    __shared__ int ns[MM];
    int c = blockIdx.x, tid = threadIdx.x, wave = tid >> 6, lane = tid & 63;
    for (int i = tid; i < MM; i += 256) {
        ks[i] = tkey[(long)c * MM + i];
        ns[i] = tnode[(long)c * MM + i];
    }
    __syncthreads();
    for (int step = 1; step < NB; step <<= 1) {
        int npair2 = NB / (2 * step);
        for (int pr = wave; pr < npair2; pr += 4) {
            int ra = pr * 2 * step, rb = ra + step;
            ull ka = ks[(ra << 6) + lane];       int na = ns[(ra << 6) + lane];
            ull kb = ks[(rb << 6) + 63 - lane];  int nb2 = ns[(rb << 6) + 63 - lane];
            if (gt(kb, nb2, ka, na)) { ka = kb; na = nb2; }
            wmerge64(ka, na, lane);
            ks[(ra << 6) + lane] = ka; ns[(ra << 6) + lane] = na;
        }
        __syncthreads();
    }
    int count = min(cnt[c * CNT_STRIDE], cap);
    int nsel = min(count, KK);
    if (tid < KK && tid < nsel) {
        int n = ns[tid];
        out[t * CC * KK + c * KK + tid] = (float)keyord(ks[tid]);     // outs
        out[NIT * CC * KK + t * CC * KK + c * KK + tid] = (float)n;   // exps
        last[c * KK + tid] = n;
        known[n] = t + 1;               // stamp: invisible to this iteration's tests
        atomicOr(&cate[n], 1u << c);
    }
    // fill path (fewer valid than K): lowest-index invalid nodes, prob=-1e9.
    // stamp test (known[n] <= t) sees only pre-iteration state -> race-free vs
    // concurrent t+1 stamps from other classes (matches reference semantics).
    if (tid == 0 && nsel < KK) {
        int r = nsel;
        for (int n = 0; n < NN && r < KK; ++n) {
            bool valid = ((nbr[n] >> c) & 1u) && (known[n] > t);
            if (!valid) {
                out[t * CC * KK + c * KK + r] = -1e9f;
                out[NIT * CC * KK + t * CC * KK + c * KK + r] = (float)n;
                last[c * KK + r] = n;
                known[n] = t + 1;
                atomicOr(&cate[n], 1u << c);
                ++r;
            }
        }
    }
}

// -------------------- host launcher: 17 launches total --------------------

extern "C" void kernel_launch(void* const* d_in, const int* in_sizes, int n_in,
                              void* d_out, int out_size, void* d_ws, size_t ws_size,
                              hipStream_t stream) {
    const float* es    = (const float*)d_in[0];
    const int*   edge  = (const int*)d_in[1];
    const int*   seeds = (const int*)d_in[2];
    const float* W     = (const float*)d_in[3];
    float* out = (float*)d_out;

    char* p = (char*)d_ws;
    auto alloc = [&](size_t bytes) -> char* {
        char* r = p;
        p += (bytes + 255) & ~(size_t)255;
        return r;
    };
    int*      known    = (int*)alloc((size_t)NN * 4);
    unsigned* cate     = (unsigned*)alloc((size_t)NN * 4);
    unsigned* nbr      = (unsigned*)alloc((size_t)NN * 4);
    double*   hx       = (double*)alloc(CC * DD * 8);
    double*   hxn      = (double*)alloc(CC * DD * 8);
    int*      last     = (int*)alloc(CC * KK * 4);
    int*      cnt      = (int*)alloc(CC * CNT_STRIDE * 4);
    ull*      tkey     = (ull*)alloc((size_t)CC * MM * 8);
    int*      tnode    = (int*)alloc((size_t)CC * MM * 4);
    size_t used = (size_t)(p - (char*)d_ws);
    size_t rem = (ws_size > used + 8192) ? (ws_size - used - 8192) : 0;
    long capl = (long)(rem / (CC * 12));
    if (capl > NN) capl = NN;
    if (capl < 1) capl = 1;
    int cap = (int)capl;
    int*    cidx = (int*)alloc((size_t)CC * cap * 4);
    ull*    ckey = (ull*)alloc((size_t)CC * cap * 8);

    k_init<<<(NN + 3) / 4, 256, 0, stream>>>(seeds, known, cate, nbr);

    for (int t = 0; t < NIT; ++t) {
        k_memedge<<<CC + EBLK, 256, 0, stream>>>(es, W, seeds, last, hx, hxn, out,
                                                 cnt, edge, cate, nbr, t);
        k_cand<<<(NN + 255) / 256, 256, 0, stream>>>(es, known, nbr, hxn,
                                                     cnt, cidx, ckey, cap, t);
        k_top<<<CC * NB, 256, 0, stream>>>(cnt, cidx, ckey, cap, tkey, tnode);
        k_mergeupd<<<CC, 256, 0, stream>>>(cnt, tkey, tnode, known, nbr,
                                           cate, last, out, cap, t);
    }
}